// Round 10
// baseline (224.462 us; speedup 1.0000x reference)
//
#include <hip/hip_runtime.h>

#define D 128
#define NB_SHIFT 5              // 32 nodes per bucket
#define BKT_NODES 32
#define PB 128                  // partition blocks
#define MAXB 1600               // >= B = ceil(50000/32) = 1563
#define S2CAP 768               // LDS edge capacity per bucket (mean ~512, sd ~23)

typedef __attribute__((ext_vector_type(8))) short bf16x8;
typedef __attribute__((ext_vector_type(4))) float f32x4;

__device__ __forceinline__ short f2bf_rne(float f) {
  unsigned u = __float_as_uint(f);
  unsigned r = u + 0x7fffu + ((u >> 16) & 1u);
  return (short)(r >> 16);
}

__device__ __forceinline__ bf16x8 pack_bf16x8(float4 a, float4 b) {
  bf16x8 h;
  h[0] = f2bf_rne(a.x); h[1] = f2bf_rne(a.y);
  h[2] = f2bf_rne(a.z); h[3] = f2bf_rne(a.w);
  h[4] = f2bf_rne(b.x); h[5] = f2bf_rne(b.y);
  h[6] = f2bf_rne(b.z); h[7] = f2bf_rne(b.w);
  return h;
}

// ---- pass 1: per-block bucket histogram -> h[block][bucket] ----
__global__ __launch_bounds__(256) void bhist_kernel(const int* __restrict__ erow,
                                                    int* __restrict__ h,
                                                    int E, int B) {
  __shared__ int lh[MAXB];
  for (int i = threadIdx.x; i < B; i += 256) lh[i] = 0;
  __syncthreads();
  const int chunk = (E + PB - 1) / PB;
  const int begin = blockIdx.x * chunk;
  const int end = min(begin + chunk, E);
  for (int e = begin + threadIdx.x; e < end; e += 256)
    atomicAdd(&lh[erow[e] >> NB_SHIFT], 1);
  __syncthreads();
  for (int i = threadIdx.x; i < B; i += 256)
    h[blockIdx.x * MAXB + i] = lh[i];
}

// ---- pass 2 (1 block, 1024 thr, 2 buckets/thread): totals + scan + windows ----
__global__ __launch_bounds__(1024) void bscan_kernel(const int* __restrict__ h,
                                                     int* __restrict__ gbcnt,
                                                     int* __restrict__ bstart,
                                                     int* __restrict__ wwin, int B) {
  __shared__ int lds[1024];
  const int t = threadIdx.x;
  const int b0 = 2 * t, b1 = 2 * t + 1;
  int c0 = 0, c1 = 0;
  if (b0 < B) {
#pragma unroll 8
    for (int bb = 0; bb < PB; ++bb) c0 += h[bb * MAXB + b0];
  }
  if (b1 < B) {
#pragma unroll 8
    for (int bb = 0; bb < PB; ++bb) c1 += h[bb * MAXB + b1];
  }
  const int v = c0 + c1;
  lds[t] = v;
  __syncthreads();
  for (int off = 1; off < 1024; off <<= 1) {
    int u = (t >= off) ? lds[t - off] : 0;
    __syncthreads();
    if (t >= off) lds[t] += u;
    __syncthreads();
  }
  const int excl = lds[t] - v;
  if (b0 < B) { gbcnt[b0] = c0; bstart[b0] = excl; }
  if (b1 < B) { gbcnt[b1] = c1; bstart[b1] = excl + c0; }
  int run0 = excl, run1 = excl + c0;
#pragma unroll 8
  for (int bb = 0; bb < PB; ++bb) {
    if (b0 < B) { wwin[bb * MAXB + b0] = run0; run0 += h[bb * MAXB + b0]; }
    if (b1 < B) { wwin[bb * MAXB + b1] = run1; run1 += h[bb * MAXB + b1]; }
  }
}

// ---- pass 3 fused: bucket partition (blocks 0..PB-1, deterministic windows) + GEMM ----
__global__ __launch_bounds__(256) void part_gemm_kernel(
    const int* __restrict__ erow, const int* __restrict__ ecol,
    const float* __restrict__ ew, const int* __restrict__ wwin,
    int2* __restrict__ swcol,
    const float* __restrict__ x, const float* __restrict__ W,
    ushort* __restrict__ y, int E, int N, int B) {
  __shared__ int lcur[MAXB];

  if (blockIdx.x < PB) {
    const int tid = threadIdx.x;
    for (int i = tid; i < B; i += 256)
      lcur[i] = wwin[blockIdx.x * MAXB + i];   // precomputed private window starts
    __syncthreads();
    const int chunk = (E + PB - 1) / PB;
    const int begin = blockIdx.x * chunk;
    const int end = min(begin + chunk, E);
    for (int e = begin + tid; e < end; e += 256) {
      int r = erow[e];
      int bkt = r >> NB_SHIFT;
      int rl = r & (BKT_NODES - 1);
      int pos = atomicAdd(&lcur[bkt], 1);      // LDS atomic only
      swcol[pos] = make_int2((rl << 16) | ecol[e], __float_as_int(ew[e]));
    }
  } else {
    // ---- GEMM: y = bf16(x @ W^T), register-resident W frags (R4-verified) ----
    const int tid = threadIdx.x;
    const int wave = tid >> 6, lane = tid & 63;
    const int m_half = wave & 1;
    const int n_half = wave >> 1;
    const int l16 = lane & 15, quad = lane >> 4;

    bf16x8 Bf[4][4];
    const float4* W4 = (const float4*)W;
#pragma unroll
    for (int nt = 0; nt < 4; ++nt) {
      int n = n_half * 64 + nt * 16 + l16;
#pragma unroll
      for (int kb = 0; kb < 4; ++kb) {
        int idx = (n * D + kb * 32 + quad * 8) >> 2;
        Bf[nt][kb] = pack_bf16x8(W4[idx], W4[idx + 1]);
      }
    }

    const float4* x4 = (const float4*)x;
    const int ntiles = (N + 63) >> 6;
    const int gstride = gridDim.x - PB;
    for (int tile = (int)blockIdx.x - PB; tile < ntiles; tile += gstride) {
      const int row0 = tile * 64 + m_half * 32;
      f32x4 acc[2][4];
#pragma unroll
      for (int mt = 0; mt < 2; ++mt)
#pragma unroll
        for (int nt = 0; nt < 4; ++nt)
          acc[mt][nt] = (f32x4){0.f, 0.f, 0.f, 0.f};

#pragma unroll
      for (int kb = 0; kb < 4; ++kb) {
        const int k0 = kb * 32 + quad * 8;
        int m0 = row0 + l16;      if (m0 > N - 1) m0 = N - 1;
        int m1 = row0 + 16 + l16; if (m1 > N - 1) m1 = N - 1;
        int i0 = (m0 * D + k0) >> 2;
        int i1 = (m1 * D + k0) >> 2;
        float4 p0 = x4[i0], q0 = x4[i0 + 1];
        float4 p1 = x4[i1], q1 = x4[i1 + 1];
        bf16x8 a0 = pack_bf16x8(p0, q0);
        bf16x8 a1 = pack_bf16x8(p1, q1);
#pragma unroll
        for (int nt = 0; nt < 4; ++nt) {
          acc[0][nt] = __builtin_amdgcn_mfma_f32_16x16x32_bf16(a0, Bf[nt][kb], acc[0][nt], 0, 0, 0);
          acc[1][nt] = __builtin_amdgcn_mfma_f32_16x16x32_bf16(a1, Bf[nt][kb], acc[1][nt], 0, 0, 0);
        }
      }

#pragma unroll
      for (int mt = 0; mt < 2; ++mt) {
        int rbase = row0 + mt * 16 + quad * 4;
#pragma unroll
        for (int nt = 0; nt < 4; ++nt) {
          int col = n_half * 64 + nt * 16 + l16;
#pragma unroll
          for (int r = 0; r < 4; ++r) {
            int row = rbase + r;
            if (row < N) y[row * D + col] = (ushort)f2bf_rne(acc[mt][nt][r]);
          }
        }
      }
    }
  }
}

// ---- pass 4 fused: in-LDS node sort + register gather. block = 32-node bucket ----
// ~12.4 KB LDS, 1563 blocks -> ~6 blocks/CU, ~24 waves/CU of latency-hiding TLP.
__global__ __launch_bounds__(256) void sort_gather_kernel(
    const int2* __restrict__ swcol, const int* __restrict__ bstart,
    const int* __restrict__ gbcnt, const ushort* __restrict__ y,
    const float* __restrict__ bias, float* __restrict__ out, int N) {
  __shared__ int2 eraw[S2CAP];                       // 6 KB raw bucket edges
  __shared__ int2 esrt[S2CAP];                       // 6 KB node-sorted edges
  __shared__ int nh[BKT_NODES], sc[BKT_NODES], ncur[BKT_NODES];

  const int b = blockIdx.x, tid = threadIdx.x;
  const int s = bstart[b];
  const int c = gbcnt[b];
  const int wave = tid >> 6, lane = tid & 63;
  const unsigned* __restrict__ y1 = (const unsigned*)y;
  const float2 bv = ((const float2*)bias)[lane];

  if (c <= S2CAP) {
    if (tid < BKT_NODES) nh[tid] = 0;
    for (int j = tid; j < c; j += 256) eraw[j] = swcol[s + j];   // single global read
    __syncthreads();
    for (int j = tid; j < c; j += 256) atomicAdd(&nh[eraw[j].x >> 16], 1);
    __syncthreads();
    if (tid < BKT_NODES) sc[tid] = nh[tid];
    __syncthreads();
    for (int off = 1; off < BKT_NODES; off <<= 1) {
      int v = 0;
      if (tid < BKT_NODES && tid >= off) v = sc[tid - off];
      __syncthreads();
      if (tid < BKT_NODES && tid >= off) sc[tid] += v;
      __syncthreads();
    }
    if (tid < BKT_NODES) ncur[tid] = sc[tid] - nh[tid];
    __syncthreads();
    for (int j = tid; j < c; j += 256) {
      int2 en = eraw[j];
      int pos = atomicAdd(&ncur[en.x >> 16], 1);
      esrt[pos] = en;
    }
    __syncthreads();

    // gather: wave-per-node (8 nodes/wave), edges broadcast from LDS
    for (int i = 0; i < 8; ++i) {
      int rl = wave * 8 + i;
      int node = (b << NB_SHIFT) + rl;
      if (node >= N) continue;
      int e1 = sc[rl];
      int e0 = e1 - nh[rl];
      float2 acc = bv;
#pragma unroll 4
      for (int j = e0; j < e1; ++j) {
        int2 en = esrt[j];                           // LDS same-address broadcast
        float wg = __int_as_float(en.y);
        unsigned v = y1[(en.x & 0xFFFF) * 64 + lane];  // 256 B/edge coalesced
        acc.x += wg * __uint_as_float(v << 16);
        acc.y += wg * __uint_as_float(v & 0xffff0000u);
      }
      ((float2*)out)[node * 64 + lane] = acc;
    }
  } else {
    // fallback (statistically unreachable: cap = mean + 11 sd): global filter
    for (int i = 0; i < 8; ++i) {
      int rl = wave * 8 + i;
      int node = (b << NB_SHIFT) + rl;
      if (node >= N) continue;
      float2 acc = bv;
      for (int j = 0; j < c; ++j) {
        int2 en = swcol[s + j];
        if ((en.x >> 16) == rl) {
          float wg = __int_as_float(en.y);
          unsigned v = y1[(en.x & 0xFFFF) * 64 + lane];
          acc.x += wg * __uint_as_float(v << 16);
          acc.y += wg * __uint_as_float(v & 0xffff0000u);
        }
      }
      ((float2*)out)[node * 64 + lane] = acc;
    }
  }
}

// ---- launch ----
extern "C" void kernel_launch(void* const* d_in, const int* in_sizes, int n_in,
                              void* d_out, int out_size, void* d_ws, size_t ws_size,
                              hipStream_t stream) {
  const float* x    = (const float*)d_in[0];
  const int*   erow = (const int*)d_in[1];
  const int*   ecol = (const int*)d_in[2];
  const float* ew   = (const float*)d_in[3];
  const float* W    = (const float*)d_in[4];
  const float* b    = (const float*)d_in[5];
  float* out = (float*)d_out;

  const int N = in_sizes[0] / D;
  const int E = in_sizes[1];
  const int B = (N + BKT_NODES - 1) >> NB_SHIFT;

  // workspace layout
  char* ws = (char*)d_ws;
  ushort* y      = (ushort*)ws;                              // N*D bf16 (12.8 MB)
  int2*   swcol  = (int2*)(ws + (size_t)N * D * 2);          // E entries (6.4 MB)
  int*    h      = (int*)(swcol + E);                        // PB*MAXB
  int*    wwin   = h + PB * MAXB;                            // PB*MAXB
  int*    gbcnt  = wwin + PB * MAXB;                         // MAXB
  int*    bstart = gbcnt + MAXB;                             // MAXB

  bhist_kernel<<<PB, 256, 0, stream>>>(erow, h, E, B);
  bscan_kernel<<<1, 1024, 0, stream>>>(h, gbcnt, bstart, wwin, B);

  const int ntiles = (N + 63) >> 6;
  part_gemm_kernel<<<PB + ntiles, 256, 0, stream>>>(
      erow, ecol, ew, wwin, swcol, x, W, y, E, N, B);

  sort_gather_kernel<<<B, 256, 0, stream>>>(swcol, bstart, gbcnt, y, b, out, N);
}

// Round 11
// 172.970 us; speedup vs baseline: 1.2977x; 1.2977x over previous
//
#include <hip/hip_runtime.h>

#define D 128
#define NB_SHIFT 5              // 32 nodes per bucket
#define BKT_NODES 32
#define PB 128                  // partition blocks
#define MAXB 1600               // >= B = ceil(50000/32) = 1563
#define S2CAP 768               // LDS edge capacity per bucket (mean ~512, sd ~23)

typedef __attribute__((ext_vector_type(8))) short bf16x8;
typedef __attribute__((ext_vector_type(4))) float f32x4;

__device__ __forceinline__ short f2bf_rne(float f) {
  unsigned u = __float_as_uint(f);
  unsigned r = u + 0x7fffu + ((u >> 16) & 1u);
  return (short)(r >> 16);
}

__device__ __forceinline__ bf16x8 pack_bf16x8(float4 a, float4 b) {
  bf16x8 h;
  h[0] = f2bf_rne(a.x); h[1] = f2bf_rne(a.y);
  h[2] = f2bf_rne(a.z); h[3] = f2bf_rne(a.w);
  h[4] = f2bf_rne(b.x); h[5] = f2bf_rne(b.y);
  h[6] = f2bf_rne(b.z); h[7] = f2bf_rne(b.w);
  return h;
}

// ---- pass 1: per-block bucket histogram -> h[block][bucket]; block 0 zeroes cursor ----
__global__ __launch_bounds__(256) void bhist_kernel(const int* __restrict__ erow,
                                                    int* __restrict__ h,
                                                    int* __restrict__ cursor,
                                                    int E, int B) {
  __shared__ int lh[MAXB];
  if (blockIdx.x == 0 && threadIdx.x == 0) cursor[0] = 0;
  for (int i = threadIdx.x; i < B; i += 256) lh[i] = 0;
  __syncthreads();
  const int chunk = (E + PB - 1) / PB;
  const int begin = blockIdx.x * chunk;
  const int end = min(begin + chunk, E);
  for (int e = begin + threadIdx.x; e < end; e += 256)
    atomicAdd(&lh[erow[e] >> NB_SHIFT], 1);
  __syncthreads();
  for (int i = threadIdx.x; i < B; i += 256)
    h[blockIdx.x * MAXB + i] = lh[i];
}

// ---- pass 2: parallel unordered window assignment, one thread per bucket ----
// Column-scan of h (coalesced across buckets), then one atomicAdd per bucket
// grabs a contiguous region. Bucket order in swcol is arbitrary — gather
// addresses through bstart[], so order doesn't matter.
__global__ __launch_bounds__(256) void winassign_kernel(
    const int* __restrict__ h, int* __restrict__ cursor,
    int* __restrict__ gbcnt, int* __restrict__ bstart,
    int* __restrict__ wwin, int B) {
  const int t = blockIdx.x * 256 + threadIdx.x;
  if (t >= B) return;
  int total = 0;
#pragma unroll 8
  for (int bb = 0; bb < PB; ++bb) total += h[bb * MAXB + t];   // coalesced
  const int base = atomicAdd(cursor, total);
  gbcnt[t] = total;
  bstart[t] = base;
  int run = base;
#pragma unroll 8
  for (int bb = 0; bb < PB; ++bb) {                            // coalesced r/w
    wwin[bb * MAXB + t] = run;
    run += h[bb * MAXB + t];
  }
}

// ---- pass 3 fused: bucket partition (blocks 0..PB-1, deterministic windows) + GEMM ----
__global__ __launch_bounds__(256) void part_gemm_kernel(
    const int* __restrict__ erow, const int* __restrict__ ecol,
    const float* __restrict__ ew, const int* __restrict__ wwin,
    int2* __restrict__ swcol,
    const float* __restrict__ x, const float* __restrict__ W,
    ushort* __restrict__ y, int E, int N, int B) {
  __shared__ int lcur[MAXB];

  if (blockIdx.x < PB) {
    const int tid = threadIdx.x;
    for (int i = tid; i < B; i += 256)
      lcur[i] = wwin[blockIdx.x * MAXB + i];   // precomputed private window starts
    __syncthreads();
    const int chunk = (E + PB - 1) / PB;
    const int begin = blockIdx.x * chunk;
    const int end = min(begin + chunk, E);
    for (int e = begin + tid; e < end; e += 256) {
      int r = erow[e];
      int bkt = r >> NB_SHIFT;
      int rl = r & (BKT_NODES - 1);
      int pos = atomicAdd(&lcur[bkt], 1);      // LDS atomic only
      swcol[pos] = make_int2((rl << 16) | ecol[e], __float_as_int(ew[e]));
    }
  } else {
    // ---- GEMM: y = bf16(x @ W^T), register-resident W frags (R4-verified) ----
    const int tid = threadIdx.x;
    const int wave = tid >> 6, lane = tid & 63;
    const int m_half = wave & 1;
    const int n_half = wave >> 1;
    const int l16 = lane & 15, quad = lane >> 4;

    bf16x8 Bf[4][4];
    const float4* W4 = (const float4*)W;
#pragma unroll
    for (int nt = 0; nt < 4; ++nt) {
      int n = n_half * 64 + nt * 16 + l16;
#pragma unroll
      for (int kb = 0; kb < 4; ++kb) {
        int idx = (n * D + kb * 32 + quad * 8) >> 2;
        Bf[nt][kb] = pack_bf16x8(W4[idx], W4[idx + 1]);
      }
    }

    const float4* x4 = (const float4*)x;
    const int ntiles = (N + 63) >> 6;
    const int gstride = gridDim.x - PB;
    for (int tile = (int)blockIdx.x - PB; tile < ntiles; tile += gstride) {
      const int row0 = tile * 64 + m_half * 32;
      f32x4 acc[2][4];
#pragma unroll
      for (int mt = 0; mt < 2; ++mt)
#pragma unroll
        for (int nt = 0; nt < 4; ++nt)
          acc[mt][nt] = (f32x4){0.f, 0.f, 0.f, 0.f};

#pragma unroll
      for (int kb = 0; kb < 4; ++kb) {
        const int k0 = kb * 32 + quad * 8;
        int m0 = row0 + l16;      if (m0 > N - 1) m0 = N - 1;
        int m1 = row0 + 16 + l16; if (m1 > N - 1) m1 = N - 1;
        int i0 = (m0 * D + k0) >> 2;
        int i1 = (m1 * D + k0) >> 2;
        float4 p0 = x4[i0], q0 = x4[i0 + 1];
        float4 p1 = x4[i1], q1 = x4[i1 + 1];
        bf16x8 a0 = pack_bf16x8(p0, q0);
        bf16x8 a1 = pack_bf16x8(p1, q1);
#pragma unroll
        for (int nt = 0; nt < 4; ++nt) {
          acc[0][nt] = __builtin_amdgcn_mfma_f32_16x16x32_bf16(a0, Bf[nt][kb], acc[0][nt], 0, 0, 0);
          acc[1][nt] = __builtin_amdgcn_mfma_f32_16x16x32_bf16(a1, Bf[nt][kb], acc[1][nt], 0, 0, 0);
        }
      }

#pragma unroll
      for (int mt = 0; mt < 2; ++mt) {
        int rbase = row0 + mt * 16 + quad * 4;
#pragma unroll
        for (int nt = 0; nt < 4; ++nt) {
          int col = n_half * 64 + nt * 16 + l16;
#pragma unroll
          for (int r = 0; r < 4; ++r) {
            int row = rbase + r;
            if (row < N) y[row * D + col] = (ushort)f2bf_rne(acc[mt][nt][r]);
          }
        }
      }
    }
  }
}

// ---- pass 4 fused: in-LDS node sort + register gather. block = 32-node bucket ----
// ~12.4 KB LDS, 1563 blocks -> ~6 blocks/CU resident, ~24 waves/CU TLP.
__global__ __launch_bounds__(256) void sort_gather_kernel(
    const int2* __restrict__ swcol, const int* __restrict__ bstart,
    const int* __restrict__ gbcnt, const ushort* __restrict__ y,
    const float* __restrict__ bias, float* __restrict__ out, int N) {
  __shared__ int2 eraw[S2CAP];                       // 6 KB raw bucket edges
  __shared__ int2 esrt[S2CAP];                       // 6 KB node-sorted edges
  __shared__ int nh[BKT_NODES], sc[BKT_NODES], ncur[BKT_NODES];

  const int b = blockIdx.x, tid = threadIdx.x;
  const int s = bstart[b];
  const int c = gbcnt[b];
  const int wave = tid >> 6, lane = tid & 63;
  const unsigned* __restrict__ y1 = (const unsigned*)y;
  const float2 bv = ((const float2*)bias)[lane];

  if (c <= S2CAP) {
    if (tid < BKT_NODES) nh[tid] = 0;
    for (int j = tid; j < c; j += 256) eraw[j] = swcol[s + j];   // single global read
    __syncthreads();
    for (int j = tid; j < c; j += 256) atomicAdd(&nh[eraw[j].x >> 16], 1);
    __syncthreads();
    if (tid < BKT_NODES) sc[tid] = nh[tid];
    __syncthreads();
    for (int off = 1; off < BKT_NODES; off <<= 1) {
      int v = 0;
      if (tid < BKT_NODES && tid >= off) v = sc[tid - off];
      __syncthreads();
      if (tid < BKT_NODES && tid >= off) sc[tid] += v;
      __syncthreads();
    }
    if (tid < BKT_NODES) ncur[tid] = sc[tid] - nh[tid];
    __syncthreads();
    for (int j = tid; j < c; j += 256) {
      int2 en = eraw[j];
      int pos = atomicAdd(&ncur[en.x >> 16], 1);
      esrt[pos] = en;
    }
    __syncthreads();

    // gather: wave-per-node (8 nodes/wave), edges broadcast from LDS
    for (int i = 0; i < 8; ++i) {
      int rl = wave * 8 + i;
      int node = (b << NB_SHIFT) + rl;
      if (node >= N) continue;
      int e1 = sc[rl];
      int e0 = e1 - nh[rl];
      float2 acc = bv;
#pragma unroll 4
      for (int j = e0; j < e1; ++j) {
        int2 en = esrt[j];                           // LDS same-address broadcast
        float wg = __int_as_float(en.y);
        unsigned v = y1[(en.x & 0xFFFF) * 64 + lane];  // 256 B/edge coalesced
        acc.x += wg * __uint_as_float(v << 16);
        acc.y += wg * __uint_as_float(v & 0xffff0000u);
      }
      ((float2*)out)[node * 64 + lane] = acc;
    }
  } else {
    // fallback (statistically unreachable: cap = mean + 11 sd): global filter
    for (int i = 0; i < 8; ++i) {
      int rl = wave * 8 + i;
      int node = (b << NB_SHIFT) + rl;
      if (node >= N) continue;
      float2 acc = bv;
      for (int j = 0; j < c; ++j) {
        int2 en = swcol[s + j];
        if ((en.x >> 16) == rl) {
          float wg = __int_as_float(en.y);
          unsigned v = y1[(en.x & 0xFFFF) * 64 + lane];
          acc.x += wg * __uint_as_float(v << 16);
          acc.y += wg * __uint_as_float(v & 0xffff0000u);
        }
      }
      ((float2*)out)[node * 64 + lane] = acc;
    }
  }
}

// ---- launch ----
extern "C" void kernel_launch(void* const* d_in, const int* in_sizes, int n_in,
                              void* d_out, int out_size, void* d_ws, size_t ws_size,
                              hipStream_t stream) {
  const float* x    = (const float*)d_in[0];
  const int*   erow = (const int*)d_in[1];
  const int*   ecol = (const int*)d_in[2];
  const float* ew   = (const float*)d_in[3];
  const float* W    = (const float*)d_in[4];
  const float* b    = (const float*)d_in[5];
  float* out = (float*)d_out;

  const int N = in_sizes[0] / D;
  const int E = in_sizes[1];
  const int B = (N + BKT_NODES - 1) >> NB_SHIFT;

  // workspace layout
  char* ws = (char*)d_ws;
  ushort* y      = (ushort*)ws;                              // N*D bf16 (12.8 MB)
  int2*   swcol  = (int2*)(ws + (size_t)N * D * 2);          // E entries (6.4 MB)
  int*    h      = (int*)(swcol + E);                        // PB*MAXB
  int*    wwin   = h + PB * MAXB;                            // PB*MAXB
  int*    gbcnt  = wwin + PB * MAXB;                         // MAXB
  int*    bstart = gbcnt + MAXB;                             // MAXB
  int*    cursor = bstart + MAXB;                            // 1

  bhist_kernel<<<PB, 256, 0, stream>>>(erow, h, cursor, E, B);
  winassign_kernel<<<(B + 255) / 256, 256, 0, stream>>>(h, cursor, gbcnt, bstart, wwin, B);

  const int ntiles = (N + 63) >> 6;
  part_gemm_kernel<<<PB + ntiles, 256, 0, stream>>>(
      erow, ecol, ew, wwin, swcol, x, W, y, E, N, B);

  sort_gather_kernel<<<B, 256, 0, stream>>>(swcol, bstart, gbcnt, y, b, out, N);
}